// Round 5
// baseline (5733.984 us; speedup 1.0000x reference)
//
#include <hip/hip_runtime.h>
#include <hip/hip_bf16.h>
#include <cmath>

// Problem dims (fixed)
#define B_ 64
#define L_ 197
#define D_ 768
#define H_ 12
#define NL_ 12
#define F_ 3072
#define M_ (B_*L_)          // 12608
#define MPAD_ 12800         // 256*50

typedef __bf16 bf16_t;
typedef __bf16 bf16x8 __attribute__((ext_vector_type(8)));
typedef __bf16 bf16x4 __attribute__((ext_vector_type(4)));
typedef float  f32x4  __attribute__((ext_vector_type(4)));

#define GPTR(p) ((const __attribute__((address_space(1))) void*)(p))
#define LPTR(p) ((__attribute__((address_space(3))) void*)(p))

__device__ __forceinline__ float gelu_f(float x) {
    return 0.5f * x * (1.f + erff(x * 0.70710678118654752440f));
}

template<int N> __device__ __forceinline__ void waitvm() {
    if constexpr (N == 0)      asm volatile("s_waitcnt vmcnt(0)" ::: "memory");
    else if constexpr (N == 4) asm volatile("s_waitcnt vmcnt(4)" ::: "memory");
    __builtin_amdgcn_sched_barrier(0);
}
__device__ __forceinline__ void waitlgkm0() {
    asm volatile("s_waitcnt lgkmcnt(0)" ::: "memory");
    __builtin_amdgcn_sched_barrier(0);
}

// ---------------- elementwise: h = x + pos (fp32, float4) ----------------
__global__ __launch_bounds__(256) void k_addpos4(const float4* __restrict__ x,
                                                 const float4* __restrict__ pos,
                                                 float4* __restrict__ h,
                                                 int n4, int ld4) {
    int i = blockIdx.x * 256 + threadIdx.x;
    if (i < n4) {
        float4 a = x[i];
        float4 p = pos[i % ld4];
        float4 r; r.x = a.x + p.x; r.y = a.y + p.y; r.z = a.z + p.z; r.w = a.w + p.w;
        h[i] = r;
    }
}

// ---------------- fused fp32->bf16 convert + transpose: BT[n][k] = W[k][n] ----------------
__global__ __launch_bounds__(256) void k_convT(const float* __restrict__ W,
                                               bf16_t* __restrict__ BT,
                                               int K, int N) {
    __shared__ bf16_t s[64][72];
    int tid = threadIdx.x;
    int k0 = blockIdx.x * 64, n0 = blockIdx.y * 64;
    int kr = tid >> 4, nc = (tid & 15) * 4;
    #pragma unroll
    for (int i = 0; i < 4; ++i) {
        float4 v = *(const float4*)(W + (size_t)(k0 + kr + i*16) * N + n0 + nc);
        s[kr + i*16][nc]     = (bf16_t)v.x;
        s[kr + i*16][nc + 1] = (bf16_t)v.y;
        s[kr + i*16][nc + 2] = (bf16_t)v.z;
        s[kr + i*16][nc + 3] = (bf16_t)v.w;
    }
    __syncthreads();
    int nr = tid >> 3, kc = (tid & 7) * 8;
    #pragma unroll
    for (int i = 0; i < 2; ++i) {
        bf16x8 o;
        #pragma unroll
        for (int j = 0; j < 8; ++j) o[j] = s[kc + j][nr + i*32];
        *(bf16x8*)(BT + (size_t)(n0 + nr + i*32) * K + k0 + kc) = o;
    }
}

__global__ __launch_bounds__(256) void k_pack_qkvb(const float* __restrict__ bq,
                                                   const float* __restrict__ bk,
                                                   const float* __restrict__ bv,
                                                   float* __restrict__ bqkv) {
    int i = blockIdx.x * 256 + threadIdx.x;
    if (i < D_) { bqkv[i] = bq[i]; bqkv[D_ + i] = bk[i]; bqkv[2*D_ + i] = bv[i]; }
}

// ---------------- LayerNorm: one wave per row ----------------
template<bool BF16OUT>
__global__ __launch_bounds__(256) void k_ln(const float* __restrict__ x,
                                            const float* __restrict__ g,
                                            const float* __restrict__ bsh,
                                            void* __restrict__ out) {
    int wid = threadIdx.x >> 6, lane = threadIdx.x & 63;
    size_t row = (size_t)blockIdx.x * 4 + wid;
    const float4* xr = (const float4*)(x + row * D_);
    float4 v[3];
    float s = 0.f, sq = 0.f;
    #pragma unroll
    for (int i = 0; i < 3; ++i) {
        v[i] = xr[i*64 + lane];
        s  += v[i].x + v[i].y + v[i].z + v[i].w;
        sq += v[i].x*v[i].x + v[i].y*v[i].y + v[i].z*v[i].z + v[i].w*v[i].w;
    }
    #pragma unroll
    for (int o = 1; o < 64; o <<= 1) { s += __shfl_xor(s, o); sq += __shfl_xor(sq, o); }
    float mean = s * (1.f/768.f);
    float var  = sq * (1.f/768.f) - mean*mean;
    float rstd = rsqrtf(var + 1e-6f);
    const float4* g4 = (const float4*)g;
    const float4* b4 = (const float4*)bsh;
    #pragma unroll
    for (int i = 0; i < 3; ++i) {
        float4 gg = g4[i*64 + lane], bb = b4[i*64 + lane];
        float4 r;
        r.x = (v[i].x - mean)*rstd*gg.x + bb.x;
        r.y = (v[i].y - mean)*rstd*gg.y + bb.y;
        r.z = (v[i].z - mean)*rstd*gg.z + bb.z;
        r.w = (v[i].w - mean)*rstd*gg.w + bb.w;
        if (BF16OUT) {
            bf16x4 o4; o4[0]=(bf16_t)r.x; o4[1]=(bf16_t)r.y; o4[2]=(bf16_t)r.z; o4[3]=(bf16_t)r.w;
            ((bf16x4*)((bf16_t*)out + row * D_))[i*64 + lane] = o4;
        } else {
            ((float4*)out)[row * (D_/4) + i*64 + lane] = r;
        }
    }
}

// ============ GEMM 256x256, 8-phase (m201 template port) ============
// C[M,N] = A[M,K] * BT[N,K]^T + bias.  BM=BN=256, BK=64, 512 thr = 8 waves (2M x 4N),
// per-wave 128x64 out (acc[8][4]).  LDS 128 KB: As/Bs[2 dbuf][2 half][128*64].
// Stage granularity: half-tile (128 rows x 64 K, 2 gload_lds/thread).
// Per K-tile: 4 phases {dsread quadrant frags | stage 1 half | bar | lgkm0 | 16 MFMA | bar}.
// vmcnt(4) only at phases 4 and 8.  T2 swizzle: LDS chunk b of row r = global chunk b^(r&7).
// EPI: 0 = bias->bf16 ; 1 = bias+gelu->bf16 ; 2 = bias+resid(f32)->f32
template<int EPI>
__global__ __launch_bounds__(512, 2) void k_gemm256p(
        const bf16_t* __restrict__ A, const bf16_t* __restrict__ BT,
        const float* __restrict__ bias, const float* __restrict__ resid,
        void* __restrict__ Cout, int K, int N, int NB) {
    __shared__ bf16_t As[2][2][128 * 64];
    __shared__ bf16_t Bs[2][2][128 * 64];

    const int tid = threadIdx.x, lane = tid & 63, wid = tid >> 6;
    const int g = lane >> 4, fr = lane & 15;
    const int wmh = wid >> 2;          // A half (M rows wmh*128..)
    const int wnq = wid & 3;           // N quarter; B half = wnq>>1
    const int bh  = wnq >> 1;
    const int wn_in_half = (wnq & 1) * 64;

    // bijective XCD swizzle (m204)
    int nwg = (int)gridDim.x, orig = (int)blockIdx.x;
    int qq = nwg >> 3, rr = nwg & 7;
    int xcd = orig & 7, idx = orig >> 3;
    int wg = (xcd < rr ? xcd * (qq + 1) : rr * (qq + 1) + (xcd - rr) * qq) + idx;
    int bx = wg / NB, by = wg - bx * NB;
    const int gm0 = bx * 256, gn0 = by * 256;

    // staging: thread handles chunk j*512+tid (16B). row = j*64 + (tid>>3), chunk-in-row = tid&7.
    const int srl = tid >> 3;
    const int sbk = (tid & 7) ^ (srl & 7);     // pre-swizzled source chunk

    f32x4 acc[8][4];
    #pragma unroll
    for (int i = 0; i < 8; ++i)
        #pragma unroll
        for (int j = 0; j < 4; ++j) acc[i][j] = (f32x4){0.f, 0.f, 0.f, 0.f};

    auto stageA = [&](int t, int pb, int hh) {
        const bf16_t* src = A + (size_t)(gm0 + hh*128 + srl) * K + t*64 + sbk*8;
        #pragma unroll
        for (int j = 0; j < 2; ++j)
            __builtin_amdgcn_global_load_lds(GPTR(src + (size_t)(j*64) * K),
                LPTR(&As[pb][hh][(j*512 + wid*64) * 8]), 16, 0, 0);
    };
    auto stageB = [&](int t, int pb, int hh) {
        const bf16_t* src = BT + (size_t)(gn0 + hh*128 + srl) * K + t*64 + sbk*8;
        #pragma unroll
        for (int j = 0; j < 2; ++j)
            __builtin_amdgcn_global_load_lds(GPTR(src + (size_t)(j*64) * K),
                LPTR(&Bs[pb][hh][(j*512 + wid*64) * 8]), 16, 0, 0);
    };
    auto rdA = [&](int pb, int qm, bf16x8 (&a)[4][2]) {
        #pragma unroll
        for (int mi = 0; mi < 4; ++mi) {
            const int row = qm*64 + mi*16 + fr;
            #pragma unroll
            for (int kc = 0; kc < 2; ++kc)
                a[mi][kc] = *(const bf16x8*)&As[pb][wmh][row*64 + (((kc*4 + g) ^ (row & 7)) * 8)];
        }
    };
    auto rdB = [&](int pb, int qn, bf16x8 (&b)[2][2]) {
        #pragma unroll
        for (int ni = 0; ni < 2; ++ni) {
            const int row = wn_in_half + qn*32 + ni*16 + fr;
            #pragma unroll
            for (int kc = 0; kc < 2; ++kc)
                b[ni][kc] = *(const bf16x8*)&Bs[pb][bh][row*64 + (((kc*4 + g) ^ (row & 7)) * 8)];
        }
    };
    auto mm = [&](int qm, int qn, bf16x8 (&a)[4][2], bf16x8 (&b)[2][2]) {
        #pragma unroll
        for (int kc = 0; kc < 2; ++kc)
            #pragma unroll
            for (int mi = 0; mi < 4; ++mi)
                #pragma unroll
                for (int ni = 0; ni < 2; ++ni)
                    acc[qm*4 + mi][qn*2 + ni] = __builtin_amdgcn_mfma_f32_16x16x32_bf16(
                        a[mi][kc], b[ni][kc], acc[qm*4 + mi][qn*2 + ni], 0, 0, 0);
    };

    const int NT = K >> 6, NI = NT >> 1;

    // prologue: tile0 fully + tile1's B halves (odd-tile A staged in-loop at P1/P2)
    stageA(0, 0, 0); stageA(0, 0, 1); stageB(0, 0, 0); stageB(0, 0, 1);
    stageB(1, 1, 0); stageB(1, 1, 1);
    waitvm<4>();                       // tile0 resident; B(1) may remain
    __builtin_amdgcn_s_barrier();

    bf16x8 a[4][2], b0[2][2], b1[2][2];
    for (int i = 0; i < NI; ++i) {
        const int t0 = 2*i, t1 = t0 + 1;
        const bool s2 = (t0 + 2 < NT), s3 = (t1 + 2 < NT);
        // ---- P1: Q(0,0) t0 | stage A0(t1)
        rdA(0, 0, a); rdB(0, 0, b0);
        stageA(t1, 1, 0);
        asm volatile("s_waitcnt lgkmcnt(8)" ::: "memory");
        __builtin_amdgcn_s_barrier();
        waitlgkm0();
        __builtin_amdgcn_s_setprio(1); mm(0, 0, a, b0); __builtin_amdgcn_s_setprio(0);
        __builtin_amdgcn_s_barrier();
        // ---- P2: Q(0,1) t0 | stage A1(t1)
        rdB(0, 1, b1);
        stageA(t1, 1, 1);
        __builtin_amdgcn_s_barrier();
        waitlgkm0();
        __builtin_amdgcn_s_setprio(1); mm(0, 1, a, b1); __builtin_amdgcn_s_setprio(0);
        __builtin_amdgcn_s_barrier();
        // ---- P3: Q(1,0) t0 | stage B0(t0+2)
        rdA(0, 1, a);
        if (s2) stageB(t0 + 2, 0, 0);
        __builtin_amdgcn_s_barrier();
        waitlgkm0();
        __builtin_amdgcn_s_setprio(1); mm(1, 0, a, b0); __builtin_amdgcn_s_setprio(0);
        __builtin_amdgcn_s_barrier();
        // ---- P4: Q(1,1) t0 | stage B1(t0+2) | vmcnt
        if (s2) stageB(t0 + 2, 0, 1);
        __builtin_amdgcn_s_barrier();
        __builtin_amdgcn_s_setprio(1); mm(1, 1, a, b1); __builtin_amdgcn_s_setprio(0);
        if (s2) waitvm<4>(); else waitvm<0>();
        __builtin_amdgcn_s_barrier();
        // ---- P5: Q(0,0) t1 | stage A0(t0+2)
        rdA(1, 0, a); rdB(1, 0, b0);
        if (s2) stageA(t0 + 2, 0, 0);
        asm volatile("s_waitcnt lgkmcnt(8)" ::: "memory");
        __builtin_amdgcn_s_barrier();
        waitlgkm0();
        __builtin_amdgcn_s_setprio(1); mm(0, 0, a, b0); __builtin_amdgcn_s_setprio(0);
        __builtin_amdgcn_s_barrier();
        // ---- P6: Q(0,1) t1 | stage A1(t0+2)
        rdB(1, 1, b1);
        if (s2) stageA(t0 + 2, 0, 1);
        __builtin_amdgcn_s_barrier();
        waitlgkm0();
        __builtin_amdgcn_s_setprio(1); mm(0, 1, a, b1); __builtin_amdgcn_s_setprio(0);
        __builtin_amdgcn_s_barrier();
        // ---- P7: Q(1,0) t1 | stage B0(t1+2)
        rdA(1, 1, a);
        if (s3) stageB(t1 + 2, 1, 0);
        __builtin_amdgcn_s_barrier();
        waitlgkm0();
        __builtin_amdgcn_s_setprio(1); mm(1, 0, a, b0); __builtin_amdgcn_s_setprio(0);
        __builtin_amdgcn_s_barrier();
        // ---- P8: Q(1,1) t1 | stage B1(t1+2) | vmcnt
        if (s3) stageB(t1 + 2, 1, 1);
        __builtin_amdgcn_s_barrier();
        __builtin_amdgcn_s_setprio(1); mm(1, 1, a, b1); __builtin_amdgcn_s_setprio(0);
        if (s3) waitvm<4>(); else waitvm<0>();
        __builtin_amdgcn_s_barrier();
    }

    // epilogue
    const int crow = gm0 + wmh * 128 + g * 4;
    const int ccol = gn0 + wnq * 64 + fr;
    #pragma unroll
    for (int mi = 0; mi < 8; ++mi)
        #pragma unroll
        for (int ni = 0; ni < 4; ++ni) {
            const int c = ccol + ni * 16;
            const float bval = bias[c];
            #pragma unroll
            for (int v = 0; v < 4; ++v) {
                const int rw = crow + mi * 16 + v;
                if (rw < M_) {
                    float val = acc[mi][ni][v] + bval;
                    if (EPI == 1) val = gelu_f(val);
                    if (EPI == 2) {
                        ((float*)Cout)[(size_t)rw * N + c] = val + resid[(size_t)rw * N + c];
                    } else {
                        ((bf16_t*)Cout)[(size_t)rw * N + c] = (bf16_t)val;
                    }
                }
            }
        }
}

// ---------------- Attention: one block per (b,h), full-row softmax ----------------
__global__ __launch_bounds__(256) void k_attn(const bf16_t* __restrict__ qkv,
                                              bf16_t* __restrict__ out) {
    __shared__ bf16_t VT[64][232];
    __shared__ bf16_t P[4][16][232];
    int tid = threadIdx.x, lane = tid & 63, wid = tid >> 6;
    int b = blockIdx.x / H_, hh = blockIdx.x % H_;
    const size_t base = (size_t)b * L_ * 2304 + hh * 64;

    for (int r = tid >> 3; r < L_; r += 32) {
        int cg = (tid & 7) * 8;
        bf16x8 vv = *(const bf16x8*)(qkv + base + (size_t)r * 2304 + 1536 + cg);
        #pragma unroll
        for (int j = 0; j < 8; ++j) VT[cg + j][r] = vv[j];
    }
    for (int i = tid; i < 64 * 35; i += 256) VT[i / 35][197 + i % 35] = (bf16_t)0.f;
    {
        int r = lane & 15, c0 = 208 + (lane >> 4) * 4;
        #pragma unroll
        for (int j = 0; j < 4; ++j) P[wid][r][c0 + j] = (bf16_t)0.f;
    }
    __syncthreads();

    for (int s = wid; s < 13; s += 4) {
        int q0 = s * 16;
        int qr = q0 + (lane & 15); if (qr > L_ - 1) qr = L_ - 1;
        bf16x8 qf[2];
        #pragma unroll
        for (int kk = 0; kk < 2; ++kk)
            qf[kk] = *(const bf16x8*)(qkv + base + (size_t)qr * 2304 + kk * 32 + (lane >> 4) * 8);

        f32x4 sacc[13];
        #pragma unroll
        for (int nb = 0; nb < 13; ++nb) { f32x4 z = {0.f,0.f,0.f,0.f}; sacc[nb] = z; }
        #pragma unroll
        for (int nb = 0; nb < 13; ++nb) {
            int lk = nb * 16 + (lane & 15); if (lk > L_ - 1) lk = L_ - 1;
            #pragma unroll
            for (int kk = 0; kk < 2; ++kk) {
                bf16x8 kf = *(const bf16x8*)(qkv + base + (size_t)lk * 2304 + D_ + kk * 32 + (lane >> 4) * 8);
                sacc[nb] = __builtin_amdgcn_mfma_f32_16x16x32_bf16(qf[kk], kf, sacc[nb], 0, 0, 0);
            }
        }

        float mx[4] = {-1e30f, -1e30f, -1e30f, -1e30f};
        float pv[13][4];
        #pragma unroll
        for (int nb = 0; nb < 13; ++nb) {
            bool valid = (nb * 16 + (lane & 15)) < L_;
            #pragma unroll
            for (int v = 0; v < 4; ++v) {
                float sv = valid ? sacc[nb][v] * 0.125f : -1e30f;
                pv[nb][v] = sv;
                mx[v] = fmaxf(mx[v], sv);
            }
        }
        #pragma unroll
        for (int o = 1; o < 16; o <<= 1) {
            #pragma unroll
            for (int v = 0; v < 4; ++v) mx[v] = fmaxf(mx[v], __shfl_xor(mx[v], o));
        }
        float sum[4] = {0.f, 0.f, 0.f, 0.f};
        #pragma unroll
        for (int nb = 0; nb < 13; ++nb) {
            bool valid = (nb * 16 + (lane & 15)) < L_;
            #pragma unroll
            for (int v = 0; v < 4; ++v) {
                float e2 = valid ? __expf(pv[nb][v] - mx[v]) : 0.f;
                pv[nb][v] = e2; sum[v] += e2;
            }
        }
        #pragma unroll
        for (int o = 1; o < 16; o <<= 1) {
            #pragma unroll
            for (int v = 0; v < 4; ++v) sum[v] += __shfl_xor(sum[v], o);
        }

        #pragma unroll
        for (int nb = 0; nb < 13; ++nb)
            #pragma unroll
            for (int v = 0; v < 4; ++v)
                P[wid][(lane >> 4) * 4 + v][nb * 16 + (lane & 15)] = (bf16_t)pv[nb][v];
        asm volatile("s_waitcnt lgkmcnt(0)" ::: "memory");

        f32x4 oacc[4];
        #pragma unroll
        for (int nb = 0; nb < 4; ++nb) { f32x4 z = {0.f,0.f,0.f,0.f}; oacc[nb] = z; }
        #pragma unroll
        for (int kk = 0; kk < 7; ++kk) {
            bf16x8 pf = *(const bf16x8*)&P[wid][lane & 15][kk * 32 + (lane >> 4) * 8];
            #pragma unroll
            for (int nb = 0; nb < 4; ++nb) {
                bf16x8 vf = *(const bf16x8*)&VT[nb * 16 + (lane & 15)][kk * 32 + (lane >> 4) * 8];
                oacc[nb] = __builtin_amdgcn_mfma_f32_16x16x32_bf16(pf, vf, oacc[nb], 0, 0, 0);
            }
        }

        float rs[4];
        #pragma unroll
        for (int v = 0; v < 4; ++v) rs[v] = 1.f / sum[v];
        #pragma unroll
        for (int nb = 0; nb < 4; ++nb)
            #pragma unroll
            for (int v = 0; v < 4; ++v) {
                int r = q0 + (lane >> 4) * 4 + v;
                if (r < L_)
                    out[((size_t)b * L_ + r) * D_ + hh * 64 + nb * 16 + (lane & 15)] =
                        (bf16_t)(oacc[nb][v] * rs[v]);
            }
    }
}

// ---------------- host orchestration ----------------
extern "C" void kernel_launch(void* const* d_in, const int* in_sizes, int n_in,
                              void* d_out, int out_size, void* d_ws, size_t ws_size,
                              hipStream_t stream) {
    const float* x     = (const float*)d_in[0];
    const float* pos   = (const float*)d_in[1];
    const float* ln1_g = (const float*)d_in[2];
    const float* ln1_b = (const float*)d_in[3];
    const float* Wq    = (const float*)d_in[4];
    const float* bq    = (const float*)d_in[5];
    const float* Wk    = (const float*)d_in[6];
    const float* bk    = (const float*)d_in[7];
    const float* Wv    = (const float*)d_in[8];
    const float* bv    = (const float*)d_in[9];
    const float* Wo    = (const float*)d_in[10];
    const float* bo    = (const float*)d_in[11];
    const float* ln2_g = (const float*)d_in[12];
    const float* ln2_b = (const float*)d_in[13];
    const float* W1    = (const float*)d_in[14];
    const float* b1    = (const float*)d_in[15];
    const float* W2    = (const float*)d_in[16];
    const float* b2    = (const float*)d_in[17];
    const float* lnf_g = (const float*)d_in[18];
    const float* lnf_b = (const float*)d_in[19];

    char* wsp = (char*)d_ws;
    size_t off = 0;
    auto alloc = [&](size_t bytes) -> void* {
        void* r = wsp + off;
        off += (bytes + 255) & ~(size_t)255;
        return r;
    };
    float*  h     = (float*) alloc((size_t)M_ * D_ * 4);
    bf16_t* y     = (bf16_t*)alloc((size_t)MPAD_ * D_ * 2);
    bf16_t* qkv   = (bf16_t*)alloc((size_t)M_ * 2304 * 2);
    bf16_t* attn  = (bf16_t*)alloc((size_t)MPAD_ * D_ * 2);
    bf16_t* u     = (bf16_t*)alloc((size_t)MPAD_ * F_ * 2);
    bf16_t* wqkvT = (bf16_t*)alloc((size_t)2304 * D_ * 2);
    bf16_t* woT   = (bf16_t*)alloc((size_t)D_ * D_ * 2);
    bf16_t* w1T   = (bf16_t*)alloc((size_t)F_ * D_ * 2);
    bf16_t* w2T   = (bf16_t*)alloc((size_t)D_ * F_ * 2);
    float*  bqkv  = (float*) alloc(2304 * 4);
    (void)ws_size; (void)in_sizes; (void)n_in; (void)out_size;

    {
        int n4 = M_ * D_ / 4;
        k_addpos4<<<(n4 + 255) / 256, 256, 0, stream>>>((const float4*)x, (const float4*)pos,
                                                        (float4*)h, n4, L_ * D_ / 4);
    }

    dim3 tDD (D_ / 64, D_ / 64);
    dim3 tDF (D_ / 64, F_ / 64);
    dim3 tFD (F_ / 64, D_ / 64);

    for (int l = 0; l < NL_; ++l) {
        k_convT<<<tDD, 256, 0, stream>>>(Wq + (size_t)l * D_ * D_, wqkvT,                     D_, D_);
        k_convT<<<tDD, 256, 0, stream>>>(Wk + (size_t)l * D_ * D_, wqkvT + (size_t)768 * D_,  D_, D_);
        k_convT<<<tDD, 256, 0, stream>>>(Wv + (size_t)l * D_ * D_, wqkvT + (size_t)1536 * D_, D_, D_);
        k_convT<<<tDD, 256, 0, stream>>>(Wo + (size_t)l * D_ * D_, woT, D_, D_);
        k_convT<<<tDF, 256, 0, stream>>>(W1 + (size_t)l * D_ * F_, w1T, D_, F_);
        k_convT<<<tFD, 256, 0, stream>>>(W2 + (size_t)l * F_ * D_, w2T, F_, D_);
        k_pack_qkvb<<<3, 256, 0, stream>>>(bq + l * D_, bk + l * D_, bv + l * D_, bqkv);

        k_ln<true><<<M_ / 4, 256, 0, stream>>>(h, ln1_g + l * D_, ln1_b + l * D_, y);
        k_gemm256p<0><<<dim3(50 * 9),  512, 0, stream>>>(y,    wqkvT, bqkv,                nullptr, qkv, D_, 2304, 9);
        k_attn<<<B_ * H_, 256, 0, stream>>>(qkv, attn);
        k_gemm256p<2><<<dim3(50 * 3),  512, 0, stream>>>(attn, woT,   bo + l * D_,         h,       h,   D_, D_,   3);
        k_ln<true><<<M_ / 4, 256, 0, stream>>>(h, ln2_g + l * D_, ln2_b + l * D_, y);
        k_gemm256p<1><<<dim3(50 * 12), 512, 0, stream>>>(y,    w1T,   b1 + (size_t)l * F_, nullptr, u,   D_, F_,   12);
        k_gemm256p<2><<<dim3(50 * 3),  512, 0, stream>>>(u,    w2T,   b2 + l * D_,         h,       h,   F_, D_,   3);
    }
    k_ln<false><<<M_ / 4, 256, 0, stream>>>(h, lnf_g, lnf_b, d_out);
}

// Round 6
// 4370.922 us; speedup vs baseline: 1.3118x; 1.3118x over previous
//
#include <hip/hip_runtime.h>
#include <hip/hip_bf16.h>
#include <cmath>

// Problem dims (fixed)
#define B_ 64
#define L_ 197
#define D_ 768
#define H_ 12
#define NL_ 12
#define F_ 3072
#define M_ (B_*L_)          // 12608
#define MPAD_ 12672         // 128*99

typedef __bf16 bf16_t;
typedef __bf16 bf16x8 __attribute__((ext_vector_type(8)));
typedef __bf16 bf16x4 __attribute__((ext_vector_type(4)));
typedef float  f32x4  __attribute__((ext_vector_type(4)));

#define GPTR(p) ((const __attribute__((address_space(1))) void*)(p))
#define LPTR(p) ((__attribute__((address_space(3))) void*)(p))

__device__ __forceinline__ float gelu_f(float x) {
    return 0.5f * x * (1.f + erff(x * 0.70710678118654752440f));
}

// ---------------- elementwise: h = x + pos (fp32, float4) ----------------
__global__ __launch_bounds__(256) void k_addpos4(const float4* __restrict__ x,
                                                 const float4* __restrict__ pos,
                                                 float4* __restrict__ h,
                                                 int n4, int ld4) {
    int i = blockIdx.x * 256 + threadIdx.x;
    if (i < n4) {
        float4 a = x[i];
        float4 p = pos[i % ld4];
        float4 r; r.x = a.x + p.x; r.y = a.y + p.y; r.z = a.z + p.z; r.w = a.w + p.w;
        h[i] = r;
    }
}

// ---------------- fused fp32->bf16 convert + transpose: BT[n][k] = W[k][n] ----------------
__global__ __launch_bounds__(256) void k_convT(const float* __restrict__ W,
                                               bf16_t* __restrict__ BT,
                                               int K, int N) {
    __shared__ bf16_t s[64][72];
    int tid = threadIdx.x;
    int k0 = blockIdx.x * 64, n0 = blockIdx.y * 64;
    int kr = tid >> 4, nc = (tid & 15) * 4;
    #pragma unroll
    for (int i = 0; i < 4; ++i) {
        float4 v = *(const float4*)(W + (size_t)(k0 + kr + i*16) * N + n0 + nc);
        s[kr + i*16][nc]     = (bf16_t)v.x;
        s[kr + i*16][nc + 1] = (bf16_t)v.y;
        s[kr + i*16][nc + 2] = (bf16_t)v.z;
        s[kr + i*16][nc + 3] = (bf16_t)v.w;
    }
    __syncthreads();
    int nr = tid >> 3, kc = (tid & 7) * 8;
    #pragma unroll
    for (int i = 0; i < 2; ++i) {
        bf16x8 o;
        #pragma unroll
        for (int j = 0; j < 8; ++j) o[j] = s[kc + j][nr + i*32];
        *(bf16x8*)(BT + (size_t)(n0 + nr + i*32) * K + k0 + kc) = o;
    }
}

__global__ __launch_bounds__(256) void k_pack_qkvb(const float* __restrict__ bq,
                                                   const float* __restrict__ bk,
                                                   const float* __restrict__ bv,
                                                   float* __restrict__ bqkv) {
    int i = blockIdx.x * 256 + threadIdx.x;
    if (i < D_) { bqkv[i] = bq[i]; bqkv[D_ + i] = bk[i]; bqkv[2*D_ + i] = bv[i]; }
}

// ---------------- LayerNorm: one wave per row ----------------
template<bool BF16OUT>
__global__ __launch_bounds__(256) void k_ln(const float* __restrict__ x,
                                            const float* __restrict__ g,
                                            const float* __restrict__ bsh,
                                            void* __restrict__ out) {
    int wid = threadIdx.x >> 6, lane = threadIdx.x & 63;
    size_t row = (size_t)blockIdx.x * 4 + wid;
    const float4* xr = (const float4*)(x + row * D_);
    float4 v[3];
    float s = 0.f, sq = 0.f;
    #pragma unroll
    for (int i = 0; i < 3; ++i) {
        v[i] = xr[i*64 + lane];
        s  += v[i].x + v[i].y + v[i].z + v[i].w;
        sq += v[i].x*v[i].x + v[i].y*v[i].y + v[i].z*v[i].z + v[i].w*v[i].w;
    }
    #pragma unroll
    for (int o = 1; o < 64; o <<= 1) { s += __shfl_xor(s, o); sq += __shfl_xor(sq, o); }
    float mean = s * (1.f/768.f);
    float var  = sq * (1.f/768.f) - mean*mean;
    float rstd = rsqrtf(var + 1e-6f);
    const float4* g4 = (const float4*)g;
    const float4* b4 = (const float4*)bsh;
    #pragma unroll
    for (int i = 0; i < 3; ++i) {
        float4 gg = g4[i*64 + lane], bb = b4[i*64 + lane];
        float4 r;
        r.x = (v[i].x - mean)*rstd*gg.x + bb.x;
        r.y = (v[i].y - mean)*rstd*gg.y + bb.y;
        r.z = (v[i].z - mean)*rstd*gg.z + bb.z;
        r.w = (v[i].w - mean)*rstd*gg.w + bb.w;
        if (BF16OUT) {
            bf16x4 o4; o4[0]=(bf16_t)r.x; o4[1]=(bf16_t)r.y; o4[2]=(bf16_t)r.z; o4[3]=(bf16_t)r.w;
            ((bf16x4*)((bf16_t*)out + row * D_))[i*64 + lane] = o4;
        } else {
            ((float4*)out)[row * (D_/4) + i*64 + lane] = r;
        }
    }
}

// ---------------- GEMM (m97-pure): C = A[M,K] * BT[N,K]^T + bias ----------------
// 128x128 tile, BK=64, 4 waves (2x2), single-buffer LDS 32KB, plain __syncthreads,
// NO inline-asm waits, NO sched_barriers — compiler schedules (m141 lesson).
// T2 involution swizzle on LDS (pre-swizzled gload source + XOR'd ds_read).
// by-fastest block order + bijective XCD swizzle (L2 reuse of A-panel).
// EPI: 0 = bias->bf16 ; 1 = bias+gelu->bf16 ; 2 = bias+resid(f32)->f32
template<int EPI>
__global__ __launch_bounds__(256, 3) void k_gemm_bt(
        const bf16_t* __restrict__ A, const bf16_t* __restrict__ BT,
        const float* __restrict__ bias, const float* __restrict__ resid,
        void* __restrict__ Cout, int K, int N, int NB) {
    __shared__ bf16_t As[128 * 64];
    __shared__ bf16_t Bs[128 * 64];

    const int tid = threadIdx.x, lane = tid & 63, wid = tid >> 6;
    const int g = lane >> 4, fr = lane & 15;
    const int wm = (wid >> 1) * 64, wn = (wid & 1) * 64;

    // bijective XCD swizzle (m204); by fastest within chunk
    int nwg = (int)gridDim.x, orig = (int)blockIdx.x;
    int qq = nwg >> 3, rr = nwg & 7;
    int xcd = orig & 7, idx = orig >> 3;
    int wg = (xcd < rr ? xcd * (qq + 1) : rr * (qq + 1) + (xcd - rr) * qq) + idx;
    int bx = wg / NB, by = wg - bx * NB;
    const int gm0 = bx * 128, gn0 = by * 128;

    // staging: wave stages 32 rows of A and of B; lane l -> row base+ (l>>3), chunk l&7.
    // involution: LDS chunk c of row r holds global chunk c^(r&7).
    const int srl = lane >> 3;
    const int sc = ((lane & 7) ^ srl) * 8;

    f32x4 acc[4][4];
    #pragma unroll
    for (int i = 0; i < 4; ++i)
        #pragma unroll
        for (int j = 0; j < 4; ++j) acc[i][j] = (f32x4){0.f, 0.f, 0.f, 0.f};

    const bf16_t* a_src = A  + (size_t)(gm0 + wid * 32 + srl) * K + sc;
    const bf16_t* b_src = BT + (size_t)(gn0 + wid * 32 + srl) * K + sc;

    const int NT = K >> 6;
    for (int t = 0; t < NT; ++t) {
        const int k0 = t * 64;
        __syncthreads();                 // all waves done reading previous tile
        #pragma unroll
        for (int i = 0; i < 4; ++i) {
            __builtin_amdgcn_global_load_lds(GPTR(a_src + (size_t)(i * 8) * K + k0),
                                             LPTR(&As[(wid * 32 + i * 8) * 64]), 16, 0, 0);
            __builtin_amdgcn_global_load_lds(GPTR(b_src + (size_t)(i * 8) * K + k0),
                                             LPTR(&Bs[(wid * 32 + i * 8) * 64]), 16, 0, 0);
        }
        __syncthreads();                 // compiler drains vmcnt before barrier -> tile resident

        bf16x8 af[4][2], bf[4][2];
        #pragma unroll
        for (int mi = 0; mi < 4; ++mi) {
            const int row = wm + mi * 16 + fr;
            #pragma unroll
            for (int kc = 0; kc < 2; ++kc)
                af[mi][kc] = *(const bf16x8*)&As[row * 64 + (((kc * 4 + g) ^ (row & 7)) * 8)];
        }
        #pragma unroll
        for (int ni = 0; ni < 4; ++ni) {
            const int row = wn + ni * 16 + fr;
            #pragma unroll
            for (int kc = 0; kc < 2; ++kc)
                bf[ni][kc] = *(const bf16x8*)&Bs[row * 64 + (((kc * 4 + g) ^ (row & 7)) * 8)];
        }
        #pragma unroll
        for (int kc = 0; kc < 2; ++kc)
            #pragma unroll
            for (int mi = 0; mi < 4; ++mi)
                #pragma unroll
                for (int ni = 0; ni < 4; ++ni)
                    acc[mi][ni] = __builtin_amdgcn_mfma_f32_16x16x32_bf16(
                        af[mi][kc], bf[ni][kc], acc[mi][ni], 0, 0, 0);
    }

    const int crow = gm0 + wm + g * 4;
    const int ccol = gn0 + wn + fr;
    #pragma unroll
    for (int mi = 0; mi < 4; ++mi)
        #pragma unroll
        for (int ni = 0; ni < 4; ++ni) {
            const int c = ccol + ni * 16;
            const float bval = bias[c];
            #pragma unroll
            for (int v = 0; v < 4; ++v) {
                const int rw = crow + mi * 16 + v;
                if (rw < M_) {
                    float val = acc[mi][ni][v] + bval;
                    if (EPI == 1) val = gelu_f(val);
                    if (EPI == 2) {
                        ((float*)Cout)[(size_t)rw * N + c] = val + resid[(size_t)rw * N + c];
                    } else {
                        ((bf16_t*)Cout)[(size_t)rw * N + c] = (bf16_t)val;
                    }
                }
            }
        }
}

// ---------------- Attention: one block per (b,h), full-row softmax ----------------
__global__ __launch_bounds__(256) void k_attn(const bf16_t* __restrict__ qkv,
                                              bf16_t* __restrict__ out) {
    __shared__ bf16_t VT[64][232];
    __shared__ bf16_t P[4][16][232];
    int tid = threadIdx.x, lane = tid & 63, wid = tid >> 6;
    int b = blockIdx.x / H_, hh = blockIdx.x % H_;
    const size_t base = (size_t)b * L_ * 2304 + hh * 64;

    for (int r = tid >> 3; r < L_; r += 32) {
        int cg = (tid & 7) * 8;
        bf16x8 vv = *(const bf16x8*)(qkv + base + (size_t)r * 2304 + 1536 + cg);
        #pragma unroll
        for (int j = 0; j < 8; ++j) VT[cg + j][r] = vv[j];
    }
    for (int i = tid; i < 64 * 35; i += 256) VT[i / 35][197 + i % 35] = (bf16_t)0.f;
    {
        int r = lane & 15, c0 = 208 + (lane >> 4) * 4;
        #pragma unroll
        for (int j = 0; j < 4; ++j) P[wid][r][c0 + j] = (bf16_t)0.f;
    }
    __syncthreads();

    for (int s = wid; s < 13; s += 4) {
        int q0 = s * 16;
        int qr = q0 + (lane & 15); if (qr > L_ - 1) qr = L_ - 1;
        bf16x8 qf[2];
        #pragma unroll
        for (int kk = 0; kk < 2; ++kk)
            qf[kk] = *(const bf16x8*)(qkv + base + (size_t)qr * 2304 + kk * 32 + (lane >> 4) * 8);

        f32x4 sacc[13];
        #pragma unroll
        for (int nb = 0; nb < 13; ++nb) { f32x4 z = {0.f,0.f,0.f,0.f}; sacc[nb] = z; }
        #pragma unroll
        for (int nb = 0; nb < 13; ++nb) {
            int lk = nb * 16 + (lane & 15); if (lk > L_ - 1) lk = L_ - 1;
            #pragma unroll
            for (int kk = 0; kk < 2; ++kk) {
                bf16x8 kf = *(const bf16x8*)(qkv + base + (size_t)lk * 2304 + D_ + kk * 32 + (lane >> 4) * 8);
                sacc[nb] = __builtin_amdgcn_mfma_f32_16x16x32_bf16(qf[kk], kf, sacc[nb], 0, 0, 0);
            }
        }

        float mx[4] = {-1e30f, -1e30f, -1e30f, -1e30f};
        float pv[13][4];
        #pragma unroll
        for (int nb = 0; nb < 13; ++nb) {
            bool valid = (nb * 16 + (lane & 15)) < L_;
            #pragma unroll
            for (int v = 0; v < 4; ++v) {
                float sv = valid ? sacc[nb][v] * 0.125f : -1e30f;
                pv[nb][v] = sv;
                mx[v] = fmaxf(mx[v], sv);
            }
        }
        #pragma unroll
        for (int o = 1; o < 16; o <<= 1) {
            #pragma unroll
            for (int v = 0; v < 4; ++v) mx[v] = fmaxf(mx[v], __shfl_xor(mx[v], o));
        }
        float sum[4] = {0.f, 0.f, 0.f, 0.f};
        #pragma unroll
        for (int nb = 0; nb < 13; ++nb) {
            bool valid = (nb * 16 + (lane & 15)) < L_;
            #pragma unroll
            for (int v = 0; v < 4; ++v) {
                float e2 = valid ? __expf(pv[nb][v] - mx[v]) : 0.f;
                pv[nb][v] = e2; sum[v] += e2;
            }
        }
        #pragma unroll
        for (int o = 1; o < 16; o <<= 1) {
            #pragma unroll
            for (int v = 0; v < 4; ++v) sum[v] += __shfl_xor(sum[v], o);
        }

        #pragma unroll
        for (int nb = 0; nb < 13; ++nb)
            #pragma unroll
            for (int v = 0; v < 4; ++v)
                P[wid][(lane >> 4) * 4 + v][nb * 16 + (lane & 15)] = (bf16_t)pv[nb][v];
        asm volatile("s_waitcnt lgkmcnt(0)" ::: "memory");

        f32x4 oacc[4];
        #pragma unroll
        for (int nb = 0; nb < 4; ++nb) { f32x4 z = {0.f,0.f,0.f,0.f}; oacc[nb] = z; }
        #pragma unroll
        for (int kk = 0; kk < 7; ++kk) {
            bf16x8 pf = *(const bf16x8*)&P[wid][lane & 15][kk * 32 + (lane >> 4) * 8];
            #pragma unroll
            for (int nb = 0; nb < 4; ++nb) {
                bf16x8 vf = *(const bf16x8*)&VT[nb * 16 + (lane & 15)][kk * 32 + (lane >> 4) * 8];
                oacc[nb] = __builtin_amdgcn_mfma_f32_16x16x32_bf16(pf, vf, oacc[nb], 0, 0, 0);
            }
        }

        float rs[4];
        #pragma unroll
        for (int v = 0; v < 4; ++v) rs[v] = 1.f / sum[v];
        #pragma unroll
        for (int nb = 0; nb < 4; ++nb)
            #pragma unroll
            for (int v = 0; v < 4; ++v) {
                int r = q0 + (lane >> 4) * 4 + v;
                if (r < L_)
                    out[((size_t)b * L_ + r) * D_ + hh * 64 + nb * 16 + (lane & 15)] =
                        (bf16_t)(oacc[nb][v] * rs[v]);
            }
    }
}

// ---------------- host orchestration ----------------
extern "C" void kernel_launch(void* const* d_in, const int* in_sizes, int n_in,
                              void* d_out, int out_size, void* d_ws, size_t ws_size,
                              hipStream_t stream) {
    const float* x     = (const float*)d_in[0];
    const float* pos   = (const float*)d_in[1];
    const float* ln1_g = (const float*)d_in[2];
    const float* ln1_b = (const float*)d_in[3];
    const float* Wq    = (const float*)d_in[4];
    const float* bq    = (const float*)d_in[5];
    const float* Wk    = (const float*)d_in[6];
    const float* bk    = (const float*)d_in[7];
    const float* Wv    = (const float*)d_in[8];
    const float* bv    = (const float*)d_in[9];
    const float* Wo    = (const float*)d_in[10];
    const float* bo    = (const float*)d_in[11];
    const float* ln2_g = (const float*)d_in[12];
    const float* ln2_b = (const float*)d_in[13];
    const float* W1    = (const float*)d_in[14];
    const float* b1    = (const float*)d_in[15];
    const float* W2    = (const float*)d_in[16];
    const float* b2    = (const float*)d_in[17];
    const float* lnf_g = (const float*)d_in[18];
    const float* lnf_b = (const float*)d_in[19];

    char* wsp = (char*)d_ws;
    size_t off = 0;
    auto alloc = [&](size_t bytes) -> void* {
        void* r = wsp + off;
        off += (bytes + 255) & ~(size_t)255;
        return r;
    };
    float*  h     = (float*) alloc((size_t)M_ * D_ * 4);
    bf16_t* y     = (bf16_t*)alloc((size_t)MPAD_ * D_ * 2);
    bf16_t* qkv   = (bf16_t*)alloc((size_t)M_ * 2304 * 2);
    bf16_t* attn  = (bf16_t*)alloc((size_t)MPAD_ * D_ * 2);
    bf16_t* u     = (bf16_t*)alloc((size_t)MPAD_ * F_ * 2);
    bf16_t* wqkvT = (bf16_t*)alloc((size_t)2304 * D_ * 2);
    bf16_t* woT   = (bf16_t*)alloc((size_t)D_ * D_ * 2);
    bf16_t* w1T   = (bf16_t*)alloc((size_t)F_ * D_ * 2);
    bf16_t* w2T   = (bf16_t*)alloc((size_t)D_ * F_ * 2);
    float*  bqkv  = (float*) alloc(2304 * 4);
    (void)ws_size; (void)in_sizes; (void)n_in; (void)out_size;

    {
        int n4 = M_ * D_ / 4;
        k_addpos4<<<(n4 + 255) / 256, 256, 0, stream>>>((const float4*)x, (const float4*)pos,
                                                        (float4*)h, n4, L_ * D_ / 4);
    }

    dim3 tDD (D_ / 64, D_ / 64);
    dim3 tDF (D_ / 64, F_ / 64);
    dim3 tFD (F_ / 64, D_ / 64);

    for (int l = 0; l < NL_; ++l) {
        k_convT<<<tDD, 256, 0, stream>>>(Wq + (size_t)l * D_ * D_, wqkvT,                     D_, D_);
        k_convT<<<tDD, 256, 0, stream>>>(Wk + (size_t)l * D_ * D_, wqkvT + (size_t)768 * D_,  D_, D_);
        k_convT<<<tDD, 256, 0, stream>>>(Wv + (size_t)l * D_ * D_, wqkvT + (size_t)1536 * D_, D_, D_);
        k_convT<<<tDD, 256, 0, stream>>>(Wo + (size_t)l * D_ * D_, woT, D_, D_);
        k_convT<<<tDF, 256, 0, stream>>>(W1 + (size_t)l * D_ * F_, w1T, D_, F_);
        k_convT<<<tFD, 256, 0, stream>>>(W2 + (size_t)l * F_ * D_, w2T, F_, D_);
        k_pack_qkvb<<<3, 256, 0, stream>>>(bq + l * D_, bk + l * D_, bv + l * D_, bqkv);

        k_ln<true><<<M_ / 4, 256, 0, stream>>>(h, ln1_g + l * D_, ln1_b + l * D_, y);
        k_gemm_bt<0><<<dim3(99 * 18), 256, 0, stream>>>(y,    wqkvT, bqkv,                nullptr, qkv, D_, 2304, 18);
        k_attn<<<B_ * H_, 256, 0, stream>>>(qkv, attn);
        k_gemm_bt<2><<<dim3(99 * 6),  256, 0, stream>>>(attn, woT,   bo + l * D_,         h,       h,   D_, D_,   6);
        k_ln<true><<<M_ / 4, 256, 0, stream>>>(h, ln2_g + l * D_, ln2_b + l * D_, y);
        k_gemm_bt<1><<<dim3(99 * 24), 256, 0, stream>>>(y,    w1T,   b1 + (size_t)l * F_, nullptr, u,   D_, F_,   24);
        k_gemm_bt<2><<<dim3(99 * 6),  256, 0, stream>>>(u,    w2T,   b2 + l * D_,         h,       h,   F_, D_,   6);
    }
    k_ln<false><<<M_ / 4, 256, 0, stream>>>(h, lnf_g, lnf_b, d_out);
}